// Round 1
// baseline (558.443 us; speedup 1.0000x reference)
//
#include <hip/hip_runtime.h>
#include <math.h>

#define BB 8
#define CC 128
#define HH 256
#define WW 256
#define HWD 65536                      // H*W
#define NOUT (67108864)                // B*C*H*W

// d_out packing (floats): out | attn | w | alpha
#define ATTN_OFF ((size_t)NOUT)
#define W_OFF (ATTN_OFF + (size_t)BB * HWD)      // 67633152
#define ALPHA_OFF (W_OFF + (size_t)BB * CC)      // 67634176

__constant__ float g_declo[16] = {
    -0.00011747678400228192f, 0.0006754494059985568f, -0.0003917403729959771f,
    -0.00487035299301066f,    0.008746094047015655f,  0.013981027917015516f,
    -0.04408825393106472f,    -0.01736930100202211f,  0.128747426620186f,
    0.00047248457399797254f,  -0.2840155429624281f,   -0.015829105256023893f,
    0.5853546836548691f,      0.6756307362980128f,    0.3128715909144659f,
    0.05441584224308161f};

__device__ __forceinline__ float sigmoidf_(float v) {
    return 1.0f / (1.0f + expf(-v));
}

// a[t] = sum over (j,k) with sym(2j+k-14)==t of f[k], f = reversed dec_lo.
// sum over the 135 dwt outputs of one axis == a^T x  (symmetric pad, [1:] slice).
__global__ void compute_a_kernel(float* __restrict__ a_arr) {
    int t = threadIdx.x;  // 0..255
    float acc = 0.0f;
    for (int j = 0; j < 135; ++j) {
        for (int k = 0; k < 16; ++k) {
            int idx = 2 * j + k - 14;
            int s = (idx < 0) ? (-1 - idx) : ((idx >= WW) ? (511 - idx) : idx);
            if (s == t) acc += g_declo[15 - k];
        }
    }
    a_arr[t] = acc;
}

// One block per (b,h). 256 threads = 4 waves; wave wv covers channels
// [wv*32, wv*32+32); lane l covers columns 4l..4l+3 (float4).
// Outputs: avg_s/max_s per pixel (ws), partial[b*256+h][c] = a[h]*sum_w a[w]*x.
__global__ __launch_bounds__(256) void pass1_kernel(
    const float* __restrict__ x, const float* __restrict__ a_arr,
    float* __restrict__ avg_s, float* __restrict__ max_s,
    float* __restrict__ partial) {
    const int blk = blockIdx.x;  // b*256 + h
    const int b = blk >> 8;
    const int h = blk & 255;
    const int tid = threadIdx.x;
    const int wv = tid >> 6;
    const int lane = tid & 63;

    __shared__ float dotc[CC];
    __shared__ __align__(16) float lsum[4][256];
    __shared__ __align__(16) float lmax[4][256];

    const float4 a4 = reinterpret_cast<const float4*>(a_arr)[lane];
    const float ah = a_arr[h];

    float4 sum4 = {0.f, 0.f, 0.f, 0.f};
    float4 max4 = {-INFINITY, -INFINITY, -INFINITY, -INFINITY};

    const size_t base = (size_t)b * CC * HWD + (size_t)h * WW;
    for (int ccc = 0; ccc < 32; ++ccc) {
        const int c = wv * 32 + ccc;
        const float4 v =
            reinterpret_cast<const float4*>(x + base + (size_t)c * HWD)[lane];
        float dot = a4.x * v.x + a4.y * v.y + a4.z * v.z + a4.w * v.w;
#pragma unroll
        for (int off = 32; off >= 1; off >>= 1)
            dot += __shfl_down(dot, off, 64);
        if (lane == 0) dotc[c] = dot;
        sum4.x += v.x; sum4.y += v.y; sum4.z += v.z; sum4.w += v.w;
        max4.x = fmaxf(max4.x, v.x); max4.y = fmaxf(max4.y, v.y);
        max4.z = fmaxf(max4.z, v.z); max4.w = fmaxf(max4.w, v.w);
    }
    reinterpret_cast<float4*>(&lsum[wv][0])[lane] = sum4;
    reinterpret_cast<float4*>(&lmax[wv][0])[lane] = max4;
    __syncthreads();

    // combine 4 waves per column
    const int col = tid;
    float s = lsum[0][col] + lsum[1][col] + lsum[2][col] + lsum[3][col];
    float m = fmaxf(fmaxf(lmax[0][col], lmax[1][col]),
                    fmaxf(lmax[2][col], lmax[3][col]));
    const size_t po = (size_t)b * HWD + (size_t)h * WW + col;
    avg_s[po] = s * (1.0f / 128.0f);
    max_s[po] = m;
    if (tid < CC) partial[(size_t)blk * CC + tid] = dotc[tid] * ah;
}

// One block per b (128 threads = channels). Reduce partials over h,
// scale, run the squeeze-excite MLP, write w (and alpha once).
__global__ __launch_bounds__(128) void mlp_kernel(
    const float* __restrict__ partial, const float* __restrict__ fc_w1,
    const float* __restrict__ fc_w2, const float* __restrict__ weight,
    float* __restrict__ w_out, float* __restrict__ alpha_out) {
    const int b = blockIdx.x;
    const int c = threadIdx.x;
    float acc = 0.0f;
    for (int h = 0; h < HH; ++h)
        acc += partial[((size_t)(b * HH + h)) * CC + c];
    const float y = acc * (1.0f / (135.0f * 135.0f));

    __shared__ float ysh[CC];
    __shared__ float hsh[8];
    ysh[c] = y;
    __syncthreads();
    if (c < 8) {
        float ha = 0.0f;
        for (int k = 0; k < CC; ++k) ha += ysh[k] * fc_w1[c * CC + k];
        hsh[c] = fmaxf(ha, 0.0f);
    }
    __syncthreads();
    float wa = 0.0f;
#pragma unroll
    for (int i = 0; i < 8; ++i) wa += hsh[i] * fc_w2[c * 8 + i];
    w_out[b * CC + c] = sigmoidf_(wa);
    if (b == 0 && c == 0) alpha_out[0] = sigmoidf_(weight[0]);
}

// 7x7 correlation (zero pad 3) over [avg,max] -> sigmoid -> attn.
// One block per (b,h), thread = column.
__global__ __launch_bounds__(256) void conv_attn_kernel(
    const float* __restrict__ avg_s, const float* __restrict__ max_s,
    const float* __restrict__ cw, float* __restrict__ attn_out) {
    const int blk = blockIdx.x;  // b*256 + h
    const int b = blk >> 8;
    const int h = blk & 255;
    const int w = threadIdx.x;

    __shared__ float k0[49], k1[49];
    if (threadIdx.x < 49) {
        k0[threadIdx.x] = cw[threadIdx.x];
        k1[threadIdx.x] = cw[49 + threadIdx.x];
    }
    __syncthreads();

    const float* A = avg_s + (size_t)b * HWD;
    const float* M = max_s + (size_t)b * HWD;
    float acc = 0.0f;
    for (int kh = 0; kh < 7; ++kh) {
        const int ih = h + kh - 3;
        if (ih < 0 || ih >= HH) continue;
        for (int kw = 0; kw < 7; ++kw) {
            const int iw = w + kw - 3;
            if (iw < 0 || iw >= WW) continue;
            const float a = A[ih * WW + iw];
            const float m = M[ih * WW + iw];
            acc = fmaf(k0[kh * 7 + kw], a, acc);
            acc = fmaf(k1[kh * 7 + kw], m, acc);
        }
    }
    attn_out[(size_t)b * HWD + (size_t)h * WW + w] = sigmoidf_(acc);
}

// out = x * (alpha*attn + (1-alpha)*w[b,c]), float4 per thread.
__global__ __launch_bounds__(256) void final_mix_kernel(
    const float* __restrict__ x, const float* __restrict__ attn,
    const float* __restrict__ wvec, const float* __restrict__ weight,
    float* __restrict__ out) {
    const size_t i4 = (size_t)blockIdx.x * 256 + threadIdx.x;
    const size_t flat = i4 * 4;
    const int b = (int)(flat >> 23);                 // C*H*W = 2^23
    const int rem = (int)(flat & ((1u << 23) - 1));
    const int c = rem >> 16;                          // H*W = 2^16
    const int hw = rem & (HWD - 1);

    const float alpha = sigmoidf_(weight[0]);
    const float wc = (1.0f - alpha) * wvec[b * CC + c];

    const float4 x4 = reinterpret_cast<const float4*>(x)[i4];
    const float4 a4 =
        *reinterpret_cast<const float4*>(attn + (size_t)b * HWD + hw);
    float4 o;
    o.x = x4.x * fmaf(alpha, a4.x, wc);
    o.y = x4.y * fmaf(alpha, a4.y, wc);
    o.z = x4.z * fmaf(alpha, a4.z, wc);
    o.w = x4.w * fmaf(alpha, a4.w, wc);
    reinterpret_cast<float4*>(out)[i4] = o;
}

extern "C" void kernel_launch(void* const* d_in, const int* in_sizes, int n_in,
                              void* d_out, int out_size, void* d_ws,
                              size_t ws_size, hipStream_t stream) {
    const float* x = (const float*)d_in[0];
    const float* conv_w = (const float*)d_in[1];
    const float* fc_w1 = (const float*)d_in[2];
    const float* fc_w2 = (const float*)d_in[3];
    const float* weight = (const float*)d_in[4];

    float* out = (float*)d_out;
    float* attn_out = out + ATTN_OFF;
    float* w_out = out + W_OFF;
    float* alpha_out = out + ALPHA_OFF;

    // workspace layout (floats)
    float* wsf = (float*)d_ws;
    float* a_arr = wsf;                         // 256
    float* avg_s = wsf + 256;                   // 8*65536
    float* max_s = avg_s + (size_t)BB * HWD;    // 8*65536
    float* partial = max_s + (size_t)BB * HWD;  // 2048*128

    compute_a_kernel<<<1, 256, 0, stream>>>(a_arr);
    pass1_kernel<<<BB * HH, 256, 0, stream>>>(x, a_arr, avg_s, max_s, partial);
    mlp_kernel<<<BB, 128, 0, stream>>>(partial, fc_w1, fc_w2, weight, w_out,
                                       alpha_out);
    conv_attn_kernel<<<BB * HH, 256, 0, stream>>>(avg_s, max_s, conv_w,
                                                  attn_out);
    final_mix_kernel<<<NOUT / 4 / 256, 256, 0, stream>>>(x, attn_out, w_out,
                                                         weight, out);
}